// Round 1
// baseline (215.483 us; speedup 1.0000x reference)
//
#include <hip/hip_runtime.h>

// Problem constants (from reference): P=8 patch, N=16 slots, WS=32 window,
// B=8, C=12, H=W=512. ref_x/ref_y are runtime device scalars.
#define PP    8
#define NSEL  16
#define WSZ   32

// One block per (b,c). 256 threads.
__global__ __launch_bounds__(256) void patches_select_kernel(
    const float* __restrict__ d_re,
    const float* __restrict__ d_im,
    const int*   __restrict__ p_rx,
    const int*   __restrict__ p_ry,
    float*       __restrict__ out,
    int H, int W)
{
    const int bc  = blockIdx.x;      // b*C + c
    const int tid = threadIdx.x;

    const int rx = p_rx[0];
    const int ry = p_ry[0];
    const int wx0 = max(rx - WSZ / 2, 0);
    const int wx1 = min(rx + WSZ / 2, H);
    const int wy0 = max(ry - WSZ / 2, 0);
    const int wy1 = min(ry + WSZ / 2, W);
    const int Wh = wx1 - wx0;
    const int Ww = wy1 - wy0;
    const int Ph = Wh - PP + 1;
    const int Pw = Ww - PP + 1;
    const int M  = Ph * Pw;          // <= 625

    __shared__ float sre[WSZ][WSZ];      // window, real
    __shared__ float sim[WSZ][WSZ];      // window, imag
    __shared__ float sref[PP][PP][2];    // reference patch
    __shared__ float dists[WSZ * WSZ];   // M distances (<=625)
    __shared__ int   selIdx[NSEL];

    const size_t plane = (size_t)H * W;
    const float* baseR = d_re + (size_t)bc * plane;
    const float* baseI = d_im + (size_t)bc * plane;

    // ---- stage window into LDS (coalesced row reads) ----
    for (int t = tid; t < Wh * Ww; t += 256) {
        const int i = t / Ww, j = t - i * Ww;
        const size_t g = (size_t)(wx0 + i) * W + (wy0 + j);
        sre[i][j] = baseR[g];
        sim[i][j] = baseI[g];
    }
    // ---- stage reference patch (taken from global, matches reference slice) ----
    for (int t = tid; t < PP * PP; t += 256) {
        const int i = t / PP, j = t - i * PP;
        const size_t g = (size_t)(rx + i) * W + (ry + j);
        sref[i][j][0] = baseR[g];
        sref[i][j][1] = baseI[g];
    }
    __syncthreads();

    // ---- distances: replicate numpy pairwise_sum(128) bit-exactly ----
    // Element order e = (dx*8 + dy)*2 + comp (contiguous order of diff array).
    // numpy: r[0..7] accumulate stride-8 groups; combine ((r0+r1)+(r2+r3))+((r4+r5)+(r6+r7)).
    // 0.0f + x == x bitwise for x>=0, so zero-init + add matches r[j]=a[j] init.
    // __f*_rn intrinsics forbid FMA contraction (numpy rounds mul and add separately).
    for (int m = tid; m < M; m += 256) {
        const int pi = m / Pw, pj = m - pi * Pw;
        float r[8];
#pragma unroll
        for (int j = 0; j < 8; ++j) r[j] = 0.0f;
        // group k covers e = 8k..8k+7  ->  dx = k>>1, dy base = (k&1)*4
#pragma unroll
        for (int k = 0; k < 16; ++k) {
            const int dx  = k >> 1;
            const int dyb = (k & 1) * 4;
#pragma unroll
            for (int j = 0; j < 8; ++j) {
                const int dy   = dyb + (j >> 1);
                const int comp = j & 1;
                const float w  = comp ? sim[pi + dx][pj + dy] : sre[pi + dx][pj + dy];
                const float rf = sref[dx][dy][comp];
                const float dl = __fsub_rn(w, rf);
                const float sq = __fmul_rn(dl, dl);
                r[j] = __fadd_rn(r[j], sq);
            }
        }
        const float s0 = __fadd_rn(__fadd_rn(r[0], r[1]), __fadd_rn(r[2], r[3]));
        const float s1 = __fadd_rn(__fadd_rn(r[4], r[5]), __fadd_rn(r[6], r[7]));
        const float S  = __fadd_rn(s0, s1);
        // 0.5 * (S / 128): both exact power-of-two scalings -> S * (1/256) exact.
        dists[m] = S * (1.0f / 256.0f);
    }
    __syncthreads();

    // ---- sequential slot insertion (order-dependent; must match scan order) ----
    // Wave 0 only: lane l<16 holds slot l. For each patch m in order, the FIRST
    // slot with nd > d gets replaced. Ballot + ffs finds it in O(1).
    if (tid < 64) {
        float nd  = (tid < NSEL) ? 1e33f : -1.0f;  // lanes >=16 never match (d >= 0)
        int   mi  = -1;
        for (int m = 0; m < M; ++m) {
            const float d = dists[m];
            const unsigned long long mask = __ballot(nd > d);
            if (mask) {
                const int first = __ffsll(mask) - 1;
                if (tid == first) { nd = d; mi = m; }
            }
        }
        if (tid < NSEL) selIdx[tid] = mi;
    }
    __syncthreads();

    // ---- write 16 selected patches: out[bc][slot][k][comp], k = dx*8+dy ----
    float* obase = out + (size_t)bc * (NSEL * PP * PP * 2);
    for (int t = tid; t < NSEL * PP * PP * 2; t += 256) {
        const int slot = t >> 7;          // /128
        const int rem  = t & 127;
        const int k    = rem >> 1;
        const int comp = rem & 1;
        const int m    = selIdx[slot];
        float v = 0.0f;                   // unfilled slot -> zeros (matches init ns)
        if (m >= 0) {
            const int pi = m / Pw, pj = m - pi * Pw;
            const int dx = k >> 3, dy = k & 7;
            v = comp ? sim[pi + dx][pj + dy] : sre[pi + dx][pj + dy];
        }
        obase[t] = v;
    }
}

extern "C" void kernel_launch(void* const* d_in, const int* in_sizes, int n_in,
                              void* d_out, int out_size, void* d_ws, size_t ws_size,
                              hipStream_t stream) {
    const float* d_re = (const float*)d_in[0];
    const float* d_im = (const float*)d_in[1];
    const int*   p_rx = (const int*)d_in[2];
    const int*   p_ry = (const int*)d_in[3];
    float* out = (float*)d_out;

    const int H = 512, W = 512;
    const int BC = in_sizes[0] / (H * W);   // 8*12 = 96

    patches_select_kernel<<<BC, 256, 0, stream>>>(d_re, d_im, p_rx, p_ry, out, H, W);
}

// Round 2
// 196.673 us; speedup vs baseline: 1.0956x; 1.0956x over previous
//
#include <hip/hip_runtime.h>
#include <math.h>

// Problem constants (from reference): P=8 patch, N=16 slots, WS=32 window,
// B=8, C=12, H=W=512. ref_x/ref_y are runtime device scalars.
#define PP    8
#define NSEL  16
#define WSZ   32

// One block per (b,c). 256 threads.
__global__ __launch_bounds__(256) void patches_select_kernel(
    const float* __restrict__ d_re,
    const float* __restrict__ d_im,
    const int*   __restrict__ p_rx,
    const int*   __restrict__ p_ry,
    float*       __restrict__ out,
    int H, int W)
{
    const int bc  = blockIdx.x;      // b*C + c
    const int tid = threadIdx.x;

    const int rx = p_rx[0];
    const int ry = p_ry[0];
    const int wx0 = max(rx - WSZ / 2, 0);
    const int wx1 = min(rx + WSZ / 2, H);
    const int wy0 = max(ry - WSZ / 2, 0);
    const int wy1 = min(ry + WSZ / 2, W);
    const int Wh = wx1 - wx0;
    const int Ww = wy1 - wy0;
    const int Ph = Wh - PP + 1;
    const int Pw = Ww - PP + 1;
    const int M  = Ph * Pw;                 // <= 625
    const int Mpad = (M + 15) & ~15;        // <= 640, fits dists[1024]

    __shared__ float sre[WSZ][WSZ];      // window, real
    __shared__ float sim[WSZ][WSZ];      // window, imag
    __shared__ float sref[PP][PP][2];    // reference patch
    __shared__ float dists[WSZ * WSZ];   // M distances + INF padding
    __shared__ int   selIdx[NSEL];

    const size_t plane = (size_t)H * W;
    const float* baseR = d_re + (size_t)bc * plane;
    const float* baseI = d_im + (size_t)bc * plane;

    // ---- stage window into LDS (coalesced row reads) ----
    for (int t = tid; t < Wh * Ww; t += 256) {
        const int i = t / Ww, j = t - i * Ww;
        const size_t g = (size_t)(wx0 + i) * W + (wy0 + j);
        sre[i][j] = baseR[g];
        sim[i][j] = baseI[g];
    }
    // ---- stage reference patch ----
    for (int t = tid; t < PP * PP; t += 256) {
        const int i = t / PP, j = t - i * PP;
        const size_t g = (size_t)(rx + i) * W + (ry + j);
        sref[i][j][0] = baseR[g];
        sref[i][j][1] = baseI[g];
    }
    // ---- pad dists[M..Mpad) with +INF (never selected: nd > INF is false) ----
    if (tid < 16 && M + tid < Mpad) dists[M + tid] = INFINITY;
    __syncthreads();

    // ---- distances: replicate numpy pairwise_sum(128) bit-exactly ----
    // Element order e = (dx*8 + dy)*2 + comp (contiguous order of diff array).
    // numpy: r[0..7] accumulate stride-8 groups; combine ((r0+r1)+(r2+r3))+((r4+r5)+(r6+r7)).
    // __f*_rn intrinsics forbid FMA contraction (numpy rounds mul and add separately).
    for (int m = tid; m < M; m += 256) {
        const int pi = m / Pw, pj = m - pi * Pw;
        float r[8];
#pragma unroll
        for (int j = 0; j < 8; ++j) r[j] = 0.0f;
        // group k covers e = 8k..8k+7  ->  dx = k>>1, dy base = (k&1)*4
#pragma unroll
        for (int k = 0; k < 16; ++k) {
            const int dx  = k >> 1;
            const int dyb = (k & 1) * 4;
#pragma unroll
            for (int j = 0; j < 8; ++j) {
                const int dy   = dyb + (j >> 1);
                const int comp = j & 1;
                const float w  = comp ? sim[pi + dx][pj + dy] : sre[pi + dx][pj + dy];
                const float rf = sref[dx][dy][comp];
                const float dl = __fsub_rn(w, rf);
                const float sq = __fmul_rn(dl, dl);
                r[j] = __fadd_rn(r[j], sq);
            }
        }
        const float s0 = __fadd_rn(__fadd_rn(r[0], r[1]), __fadd_rn(r[2], r[3]));
        const float s1 = __fadd_rn(__fadd_rn(r[4], r[5]), __fadd_rn(r[6], r[7]));
        const float S  = __fadd_rn(s0, s1);
        // 0.5 * (S / 128): both exact power-of-two scalings -> S * (1/256) exact.
        dists[m] = S * (1.0f / 256.0f);
    }
    __syncthreads();

    // ---- sequential slot insertion (order-dependent; must match scan order) ----
    // Wave 0 only: lane l<16 holds slot l. For each patch m in order, the FIRST
    // slot with nd > d gets replaced (ballot + ffs). Distances are prefetched in
    // register batches of 16 (double-buffered) so the dependent chain per step is
    // just cmp -> ballot -> ffs -> cndmask, no per-step LDS latency.
    if (tid < 64) {
        float nd  = (tid < NSEL) ? 1e33f : -1.0f;  // lanes >=16 never match (d >= 0)
        int   mi  = -1;
        float cur[16];
#pragma unroll
        for (int u = 0; u < 16; ++u) cur[u] = dists[u];
        for (int m0 = 0; m0 < Mpad; m0 += 16) {
            float nxt[16];
            const int nb = m0 + 16;
            if (nb < Mpad) {
#pragma unroll
                for (int u = 0; u < 16; ++u) nxt[u] = dists[nb + u];
            } else {
#pragma unroll
                for (int u = 0; u < 16; ++u) nxt[u] = INFINITY;
            }
#pragma unroll
            for (int u = 0; u < 16; ++u) {
                const unsigned long long mask = __ballot(nd > cur[u]);
                const int first = __ffsll(mask) - 1;   // -1 if mask==0: matches no lane
                if (tid == first) { nd = cur[u]; mi = m0 + u; }
            }
#pragma unroll
            for (int u = 0; u < 16; ++u) cur[u] = nxt[u];
        }
        if (tid < NSEL) selIdx[tid] = mi;
    }
    __syncthreads();

    // ---- write 16 selected patches: out[bc][slot][k][comp], k = dx*8+dy ----
    float* obase = out + (size_t)bc * (NSEL * PP * PP * 2);
    for (int t = tid; t < NSEL * PP * PP * 2; t += 256) {
        const int slot = t >> 7;          // /128
        const int rem  = t & 127;
        const int k    = rem >> 1;
        const int comp = rem & 1;
        const int m    = selIdx[slot];
        float v = 0.0f;                   // unfilled slot -> zeros (matches init ns)
        if (m >= 0) {
            const int pi = m / Pw, pj = m - pi * Pw;
            const int dx = k >> 3, dy = k & 7;
            v = comp ? sim[pi + dx][pj + dy] : sre[pi + dx][pj + dy];
        }
        obase[t] = v;
    }
}

extern "C" void kernel_launch(void* const* d_in, const int* in_sizes, int n_in,
                              void* d_out, int out_size, void* d_ws, size_t ws_size,
                              hipStream_t stream) {
    const float* d_re = (const float*)d_in[0];
    const float* d_im = (const float*)d_in[1];
    const int*   p_rx = (const int*)d_in[2];
    const int*   p_ry = (const int*)d_in[3];
    float* out = (float*)d_out;

    const int H = 512, W = 512;
    const int BC = in_sizes[0] / (H * W);   // 8*12 = 96

    patches_select_kernel<<<BC, 256, 0, stream>>>(d_re, d_im, p_rx, p_ry, out, H, W);
}